// Round 1
// baseline (388.843 us; speedup 1.0000x reference)
//
#include <hip/hip_runtime.h>
#include <math.h>

#define TEMPC   0.07f
#define NBK     15
#define HALFK   7
#define NPOS    225      // 15*15
#define DD      128
#define HHH     256
#define WWW     256
#define NSAMP   256
#define EPSC    1e-8f

__global__ __launch_bounds__(256) void lcl_main(
    const float* __restrict__ feat,
    const int*   __restrict__ targ,
    const int*   __restrict__ anch_h,
    const int*   __restrict__ anch_w,
    float*       __restrict__ loss_acc,
    int*         __restrict__ cnt_acc)
{
    const int bn   = blockIdx.x;          // b * NSAMP + n
    const int b    = bn >> 8;             // NSAMP == 256
    const int tid  = threadIdx.x;
    const int lane = tid & 63;
    const int wave = tid >> 6;

    __shared__ float af[DD];
    __shared__ float red[4], red2[4], red3[4];
    __shared__ float s_an;
    __shared__ float s_max;

    const int ah = anch_h[bn];
    const int aw = anch_w[bn];
    const int* lab = targ + b * (HHH * WWW);
    const int alab = lab[ah * WWW + aw];
    const float* fb = feat + (size_t)b * DD * HHH * WWW;

    // ---- phase 1: stage anchor feature into LDS, reduce its squared norm ----
    float sqa = 0.f;
    if (tid < DD) {
        float v = fb[(size_t)tid * (HHH * WWW) + ah * WWW + aw];
        af[tid] = v;
        sqa = v * v;
    }
    #pragma unroll
    for (int off = 32; off; off >>= 1) sqa += __shfl_down(sqa, off, 64);
    if (lane == 0) red[wave] = sqa;
    __syncthreads();
    if (tid == 0) s_an = fmaxf(sqrtf(red[0] + red[1] + red[2] + red[3]), EPSC);
    __syncthreads();
    const float an = s_an;

    // ---- phase 2: per-position dot product + patch norm ----
    const bool active = tid < NPOS;
    float dot = 0.f, sq = 0.f;
    int hh = 0, ww = 0;
    if (active) {
        const int k = tid / NBK;
        const int l = tid - k * NBK;
        hh = ah - HALFK + k;
        ww = aw - HALFK + l;
        const float* p = fb + hh * WWW + ww;
        #pragma unroll 8
        for (int d = 0; d < DD; ++d) {
            float v = p[(size_t)d * (HHH * WWW)];
            dot = fmaf(af[d], v, dot);
            sq  = fmaf(v,     v, sq);
        }
    }

    float sim = -INFINITY;
    bool  pos = false;
    if (active) {
        float pn = fmaxf(sqrtf(sq), EPSC);
        sim = dot / (an * pn * TEMPC);
        pos = (lab[hh * WWW + ww] == alab) && (tid != (HALFK * NBK + HALFK));
    }

    // ---- phase 3a: block max ----
    float m = sim;
    #pragma unroll
    for (int off = 32; off; off >>= 1) m = fmaxf(m, __shfl_down(m, off, 64));
    if (lane == 0) red[wave] = m;
    __syncthreads();
    if (tid == 0) s_max = fmaxf(fmaxf(red[0], red[1]), fmaxf(red[2], red[3]));
    __syncthreads();
    m = s_max;

    // ---- phase 3b: exp-sum, positive-sum, positive-count ----
    float e  = active ? expf(sim - m) : 0.f;
    float ps = pos ? sim : 0.f;
    float pc = pos ? 1.f : 0.f;
    #pragma unroll
    for (int off = 32; off; off >>= 1) {
        e  += __shfl_down(e,  off, 64);
        ps += __shfl_down(ps, off, 64);
        pc += __shfl_down(pc, off, 64);
    }
    if (lane == 0) { red[wave] = e; red2[wave] = ps; red3[wave] = pc; }
    __syncthreads();
    if (tid == 0) {
        float E  = red[0]  + red[1]  + red[2]  + red[3];
        float PS = red2[0] + red2[1] + red2[2] + red2[3];
        float PC = red3[0] + red3[1] + red3[2] + red3[3];
        float lse = m + logf(E);
        if (PC > 0.5f) {
            // loss_i = -(pos_mean - lse) = lse - PS/PC
            atomicAdd(loss_acc, lse - PS / PC);
            atomicAdd(cnt_acc, 1);
        }
    }
}

__global__ void lcl_finalize(const float* __restrict__ loss_acc,
                             const int*   __restrict__ cnt_acc,
                             float*       __restrict__ out)
{
    int   c = *cnt_acc;
    float t = *loss_acc;
    out[0] = (c > 0) ? (t / (float)c) : 0.f;
}

extern "C" void kernel_launch(void* const* d_in, const int* in_sizes, int n_in,
                              void* d_out, int out_size, void* d_ws, size_t ws_size,
                              hipStream_t stream) {
    const float* feat  = (const float*)d_in[0];
    const int*   targ  = (const int*)d_in[1];
    const int*   anchh = (const int*)d_in[2];
    const int*   anchw = (const int*)d_in[3];
    float* out = (float*)d_out;

    float* loss_acc = (float*)d_ws;
    int*   cnt_acc  = (int*)((char*)d_ws + sizeof(float));

    // d_ws is poisoned to 0xAA before every call — zero our accumulators.
    hipMemsetAsync(d_ws, 0, 2 * sizeof(float), stream);

    const int n_anchors = in_sizes[2];   // B * NUM_SAMPLES = 2048
    lcl_main<<<n_anchors, 256, 0, stream>>>(feat, targ, anchh, anchw, loss_acc, cnt_acc);
    lcl_finalize<<<1, 1, 0, stream>>>(loss_acc, cnt_acc, out);
}

// Round 2
// 377.987 us; speedup vs baseline: 1.0287x; 1.0287x over previous
//
#include <hip/hip_runtime.h>
#include <math.h>

#define TEMPC   0.07f
#define NBK     15
#define HALFK   7
#define NPOS    225      // 15*15
#define DD      128
#define HHH     256
#define WWW     256
#define PLANE   (HHH * WWW)   // 65536
#define EPSC    1e-8f

__global__ __launch_bounds__(256) void lcl_main(
    const float* __restrict__ feat,
    const int*   __restrict__ targ,
    const int*   __restrict__ anch_h,
    const int*   __restrict__ anch_w,
    float*       __restrict__ loss_part,
    float*       __restrict__ cnt_part)
{
    const int bn   = blockIdx.x;          // b * NUM_SAMPLES + n
    const int b    = bn >> 8;             // NUM_SAMPLES == 256
    const int tid  = threadIdx.x;
    const int lane = tid & 63;
    const int wave = tid >> 6;

    __shared__ float af[DD];
    __shared__ float red[4], red2[4], red3[4];
    __shared__ float s_an;
    __shared__ float s_max;

    const int ah = anch_h[bn];
    const int aw = anch_w[bn];
    const int* lab = targ + b * PLANE;
    const int alab = lab[ah * WWW + aw];
    const float* fb = feat + (size_t)b * DD * PLANE;

    // ---- phase 1: stage anchor feature into LDS, reduce its squared norm ----
    float sqa = 0.f;
    if (tid < DD) {
        float v = fb[(size_t)tid * PLANE + ah * WWW + aw];
        af[tid] = v;
        sqa = v * v;
    }
    #pragma unroll
    for (int off = 32; off; off >>= 1) sqa += __shfl_down(sqa, off, 64);
    if (lane == 0) red[wave] = sqa;
    __syncthreads();
    if (tid == 0) s_an = fmaxf(sqrtf(red[0] + red[1] + red[2] + red[3]), EPSC);
    __syncthreads();
    const float an = s_an;

    // ---- phase 2: per-position dot product + patch norm ----
    const bool active = tid < NPOS;
    float dot = 0.f, sq = 0.f;
    int hh = 0, ww = 0;
    if (active) {
        const int k = tid / NBK;
        const int l = tid - k * NBK;
        hh = ah - HALFK + k;
        ww = aw - HALFK + l;
        const float* p = fb + hh * WWW + ww;
        // 32-bit element offsets (max 128*65536 < 2^31); unroll 16 for MLP
        #pragma unroll 16
        for (int d = 0; d < DD; ++d) {
            float v = p[d * PLANE];
            dot = fmaf(af[d], v, dot);
            sq  = fmaf(v,     v, sq);
        }
    }

    float sim = -INFINITY;
    bool  pos = false;
    if (active) {
        float pn = fmaxf(sqrtf(sq), EPSC);
        sim = dot / (an * pn * TEMPC);
        pos = (lab[hh * WWW + ww] == alab) && (tid != (HALFK * NBK + HALFK));
    }

    // ---- phase 3a: block max ----
    float m = sim;
    #pragma unroll
    for (int off = 32; off; off >>= 1) m = fmaxf(m, __shfl_down(m, off, 64));
    if (lane == 0) red[wave] = m;
    __syncthreads();
    if (tid == 0) s_max = fmaxf(fmaxf(red[0], red[1]), fmaxf(red[2], red[3]));
    __syncthreads();
    m = s_max;

    // ---- phase 3b: exp-sum, positive-sum, positive-count ----
    float e  = active ? expf(sim - m) : 0.f;
    float ps = pos ? sim : 0.f;
    float pc = pos ? 1.f : 0.f;
    #pragma unroll
    for (int off = 32; off; off >>= 1) {
        e  += __shfl_down(e,  off, 64);
        ps += __shfl_down(ps, off, 64);
        pc += __shfl_down(pc, off, 64);
    }
    if (lane == 0) { red[wave] = e; red2[wave] = ps; red3[wave] = pc; }
    __syncthreads();
    if (tid == 0) {
        float E  = red[0]  + red[1]  + red[2]  + red[3];
        float PS = red2[0] + red2[1] + red2[2] + red2[3];
        float PC = red3[0] + red3[1] + red3[2] + red3[3];
        float lse = m + logf(E);
        bool valid = PC > 0.5f;
        // every block writes its slot unconditionally -> no zero-init of ws needed
        loss_part[bn] = valid ? (lse - PS / PC) : 0.f;
        cnt_part[bn]  = valid ? 1.f : 0.f;
    }
}

__global__ __launch_bounds__(256) void lcl_finalize(
    const float* __restrict__ loss_part,
    const float* __restrict__ cnt_part,
    float*       __restrict__ out,
    int n)
{
    const int tid  = threadIdx.x;
    const int lane = tid & 63;
    const int wave = tid >> 6;
    __shared__ float rs[4], rc[4];

    float s = 0.f, c = 0.f;
    for (int i = tid; i < n; i += 256) {
        s += loss_part[i];
        c += cnt_part[i];
    }
    #pragma unroll
    for (int off = 32; off; off >>= 1) {
        s += __shfl_down(s, off, 64);
        c += __shfl_down(c, off, 64);
    }
    if (lane == 0) { rs[wave] = s; rc[wave] = c; }
    __syncthreads();
    if (tid == 0) {
        float S = rs[0] + rs[1] + rs[2] + rs[3];
        float C = rc[0] + rc[1] + rc[2] + rc[3];
        out[0] = (C > 0.5f) ? (S / C) : 0.f;
    }
}

extern "C" void kernel_launch(void* const* d_in, const int* in_sizes, int n_in,
                              void* d_out, int out_size, void* d_ws, size_t ws_size,
                              hipStream_t stream) {
    const float* feat  = (const float*)d_in[0];
    const int*   targ  = (const int*)d_in[1];
    const int*   anchh = (const int*)d_in[2];
    const int*   anchw = (const int*)d_in[3];
    float* out = (float*)d_out;

    const int n_anchors = in_sizes[2];   // B * NUM_SAMPLES = 2048

    float* loss_part = (float*)d_ws;
    float* cnt_part  = loss_part + n_anchors;

    lcl_main<<<n_anchors, 256, 0, stream>>>(feat, targ, anchh, anchw,
                                            loss_part, cnt_part);
    lcl_finalize<<<1, 256, 0, stream>>>(loss_part, cnt_part, out, n_anchors);
}